// Round 8
// baseline (11721.947 us; speedup 1.0000x reference)
//
#include <hip/hip_runtime.h>
#include <hip/hip_bf16.h>
#include <cstdint>
#include <cstddef>

#define NWG   256
#define NTH   512
#define LSTEP 1024

typedef __attribute__((ext_vector_type(8))) short short8;
typedef __attribute__((ext_vector_type(4))) float f32x4;
typedef __attribute__((ext_vector_type(4))) unsigned int u32x4;

__device__ __forceinline__ unsigned f2bf_bits(float x) {
  __hip_bfloat16 h = __float2bfloat16(x);
  return (unsigned)__builtin_bit_cast(unsigned short, h);
}
__device__ __forceinline__ float bfbits2f(unsigned b) {
  return __bfloat162float(__builtin_bit_cast(__hip_bfloat16, (unsigned short)b));
}
__device__ __forceinline__ float ftanh(float x) {
  const float ax = fminf(fabsf(x), 15.f);
  const float e  = __expf(-2.f * ax);
  const float t  = (1.f - e) / (1.f + e);
  return copysignf(t, x);
}
__device__ __forceinline__ float fsig(float x) {
  const float xx = fmaxf(fminf(x, 30.f), -30.f);
  return 1.f / (1.f + __expf(-xx));
}

// ws: [0,1024) flags[bc*32+jc] (tag = S+1 when State(S) visible) | [4096,+128K) stateA | stateB
// State(S) = hf after S updates, stored in buffer parity S&1.
// Grid decode: bc = wg & 7 (XCD-local bc-group under round-robin), jc = wg >> 3.

__global__ void __launch_bounds__(NTH, 2)
fused_scan(const float* __restrict__ u, const float* __restrict__ h0,
           const float* __restrict__ Wi, const float* __restrict__ bi,
           const float* __restrict__ Wm, const float* __restrict__ bm,
           float* __restrict__ out, unsigned* __restrict__ stateA,
           unsigned* __restrict__ stateB, unsigned* __restrict__ flags)
{
  __shared__ float me_s[640];      // [r8][c80], c = j16*5+g; holds bm + MFMA adds
  __shared__ float ie_s[768];      // [r8][c96], c = j16*6+g; holds bi + MFMA adds
  __shared__ float hf_own[128];    // [r8][j16]
  __shared__ float hs_own[128];
  __shared__ float bm_s[80];
  __shared__ float bi_s[96];

  const int wg   = blockIdx.x;
  const int bc   = wg & 7;         // batch-group: same-XCD under round-robin
  const int jc   = wg >> 3;        // 32 col-groups
  const int j0   = jc * 16;
  const int r0   = bc * 8;
  const int tid  = threadIdx.x;
  const int w    = tid >> 6;
  const int lane = tid & 63;
  const int colf = lane & 15;
  const int ksub = lane >> 4;

  unsigned* myflags = flags + bc * 32;          // producer slot: myflags[jc]
  const unsigned* pollp = myflags + w * 4;      // wave w's 4 producers jc=4w..4w+3

  // ---- one-time small LDS ----
  if (tid < 80) bm_s[tid] = bm[(tid % 5) * 512 + j0 + tid / 5];
  if (tid >= 128 && tid < 224) {
    const int c = tid - 128;
    bi_s[c] = bi[(c % 6) * 512 + j0 + c / 6];
  }
  // ---- init own hf/hs, publish State(0) ----
  if (tid < 128) {
    const int r = tid >> 4, j16 = tid & 15;
    const float f = h0[(size_t)(r0 + r) * 512 + j0 + j16];
    const float s = h0[(size_t)32768 + (size_t)(r0 + r) * 512 + j0 + j16];
    hf_own[tid] = f;
    hs_own[tid] = s;
    const unsigned hb = f2bf_bits(f);
    const unsigned lb = f2bf_bits(f - bfbits2f(hb));
    const unsigned pk = hb | (lb << 16);
    unsigned* dst = stateA + (size_t)(r0 + r) * 512 + j0 + j16;
    asm volatile("global_store_dword %0, %1, off sc1" :: "v"(dst), "v"(pk) : "memory");
  }
  asm volatile("s_waitcnt vmcnt(0)" ::: "memory");
  __syncthreads();   // also orders bm_s/bi_s for the accumulator init below
  // ---- init LDS accumulators with biases ----
  for (int e = tid; e < 640; e += NTH) me_s[e] = bm_s[e % 80];
  for (int e = tid; e < 768; e += NTH) ie_s[e] = bi_s[e % 96];
  __syncthreads();
  if (tid == 0) {
    unsigned* fp = myflags + jc;
    const unsigned one = 1u;
    asm volatile("global_store_dword %0, %1, off sc1" :: "v"(fp), "v"(one) : "memory");
  }

  // ---- B-fragment gathers (overlap others' init) ----
  short8 bh[5][2], bl[5][2];
  #pragma unroll
  for (int nt = 0; nt < 5; ++nt) {
    const int c = nt * 16 + colf;
    const int gcol = (c % 5) * 512 + j0 + c / 5;
    #pragma unroll
    for (int kt = 0; kt < 2; ++kt) {
      #pragma unroll
      for (int j = 0; j < 8; ++j) {
        const int kg = w * 64 + kt * 32 + ksub * 8 + j;
        const float wv = Wm[(size_t)kg * 2560 + gcol];
        const unsigned hb = f2bf_bits(wv);
        bh[nt][kt][j] = (short)hb;
        bl[nt][kt][j] = (short)f2bf_bits(wv - bfbits2f(hb));
      }
    }
  }
  const int iekc = w & 3;
  const int ienh = w >> 2;
  short8 bih[3], bil[3];
  #pragma unroll
  for (int nt = 0; nt < 3; ++nt) {
    const int c = (ienh * 3 + nt) * 16 + colf;
    const int gcol = (c % 6) * 512 + j0 + c / 6;
    #pragma unroll
    for (int j = 0; j < 8; ++j) {
      const int kg = iekc * 32 + ksub * 8 + j;
      const float wv = Wi[(size_t)kg * 3072 + gcol];
      const unsigned hb = f2bf_bits(wv);
      bih[nt][j] = (short)hb;
      bil[nt][j] = (short)f2bf_bits(wv - bfbits2f(hb));
    }
  }

  const int rloc = lane & 7;
  const float* ubase = u + (size_t)(r0 + rloc) * 131072 + iekc * 32 + ksub * 8;

  // ---- ie math: MFMA + ds_add into ie_s ----
  auto ie_math = [&](float4 xa, float4 xb) {
    const float xv[8] = {xa.x, xa.y, xa.z, xa.w, xb.x, xb.y, xb.z, xb.w};
    short8 ah, al;
    #pragma unroll
    for (int j = 0; j < 8; ++j) {
      const unsigned hb = f2bf_bits(xv[j]);
      ah[j] = (short)hb;
      al[j] = (short)f2bf_bits(xv[j] - bfbits2f(hb));
    }
    f32x4 acc[3];
    #pragma unroll
    for (int nt = 0; nt < 3; ++nt) { acc[nt][0]=0.f; acc[nt][1]=0.f; acc[nt][2]=0.f; acc[nt][3]=0.f; }
    #pragma unroll
    for (int nt = 0; nt < 3; ++nt) {
      acc[nt] = __builtin_amdgcn_mfma_f32_16x16x32_bf16(ah, bih[nt], acc[nt], 0, 0, 0);
      acc[nt] = __builtin_amdgcn_mfma_f32_16x16x32_bf16(ah, bil[nt], acc[nt], 0, 0, 0);
      acc[nt] = __builtin_amdgcn_mfma_f32_16x16x32_bf16(al, bih[nt], acc[nt], 0, 0, 0);
    }
    if (lane < 32) {
      const int rb = (lane >> 4) * 4;
      #pragma unroll
      for (int nt = 0; nt < 3; ++nt)
        #pragma unroll
        for (int i = 0; i < 4; ++i)
          unsafeAtomicAdd(&ie_s[(rb + i) * 96 + (ienh * 3 + nt) * 16 + colf], acc[nt][i]);
    }
  };

  // ---- ie(0) ----
  {
    const float4 xa0 = *(const float4*)ubase;
    const float4 xb0 = *(const float4*)(ubase + 4);
    ie_math(xa0, xb0);
  }

  for (int st = 0; st < LSTEP; ++st) {
    const unsigned* __restrict__ scur = (st & 1) ? stateB : stateA;
    unsigned* __restrict__ snxt       = (st & 1) ? stateA : stateB;

    // ======== phase 1: poll own 4 producers (paced), load state, MFMA ====
    {
      const unsigned tag = (unsigned)(st + 1);
      u32x4 fl;
      for (;;) {
        asm volatile("global_load_dwordx4 %0, %1, off sc1"
                     : "=&v"(fl) : "v"(pollp) : "memory");
        asm volatile("s_waitcnt vmcnt(0)" ::: "memory");
        if (fl[0] >= tag && fl[1] >= tag && fl[2] >= tag && fl[3] >= tag) break;
        __builtin_amdgcn_s_sleep(1);
      }
      __builtin_amdgcn_sched_barrier(0);

      const unsigned* base = scur + (size_t)(r0 + rloc) * 512 + w * 64 + ksub * 8;
      u32x4 q0, q1, q2, q3;
      asm volatile("global_load_dwordx4 %0, %1, off sc1" : "=&v"(q0) : "v"(base)      : "memory");
      asm volatile("global_load_dwordx4 %0, %1, off sc1" : "=&v"(q1) : "v"(base + 4)  : "memory");
      asm volatile("global_load_dwordx4 %0, %1, off sc1" : "=&v"(q2) : "v"(base + 32) : "memory");
      asm volatile("global_load_dwordx4 %0, %1, off sc1" : "=&v"(q3) : "v"(base + 36) : "memory");
      asm volatile("s_waitcnt vmcnt(0)" ::: "memory");
      __builtin_amdgcn_sched_barrier(0);
      short8 ah[2], al[2];
      #pragma unroll
      for (int j = 0; j < 4; ++j) {
        ah[0][j]     = (short)(q0[j] & 0xffffu);  al[0][j]     = (short)(q0[j] >> 16);
        ah[0][j + 4] = (short)(q1[j] & 0xffffu);  al[0][j + 4] = (short)(q1[j] >> 16);
        ah[1][j]     = (short)(q2[j] & 0xffffu);  al[1][j]     = (short)(q2[j] >> 16);
        ah[1][j + 4] = (short)(q3[j] & 0xffffu);  al[1][j + 4] = (short)(q3[j] >> 16);
      }
      f32x4 acc[5];
      #pragma unroll
      for (int nt = 0; nt < 5; ++nt) { acc[nt][0]=0.f; acc[nt][1]=0.f; acc[nt][2]=0.f; acc[nt][3]=0.f; }
      #pragma unroll
      for (int nt = 0; nt < 5; ++nt)
        #pragma unroll
        for (int kt = 0; kt < 2; ++kt) {
          acc[nt] = __builtin_amdgcn_mfma_f32_16x16x32_bf16(ah[kt], bh[nt][kt], acc[nt], 0, 0, 0);
          acc[nt] = __builtin_amdgcn_mfma_f32_16x16x32_bf16(ah[kt], bl[nt][kt], acc[nt], 0, 0, 0);
          acc[nt] = __builtin_amdgcn_mfma_f32_16x16x32_bf16(al[kt], bh[nt][kt], acc[nt], 0, 0, 0);
        }
      if (lane < 32) {
        const int rb = (lane >> 4) * 4;
        #pragma unroll
        for (int nt = 0; nt < 5; ++nt)
          #pragma unroll
          for (int i = 0; i < 4; ++i)
            unsafeAtomicAdd(&me_s[(rb + i) * 80 + nt * 16 + colf], acc[nt][i]);
      }
    }
    __syncthreads();   // sync #1 — me_s/ie_s complete for step st

    // ---- prefetch u(st+1) (plain loads; compiler manages waitcnt at use) ----
    float4 xa = {0.f, 0.f, 0.f, 0.f}, xb = {0.f, 0.f, 0.f, 0.f};
    if (st + 1 < LSTEP) {
      const float* up = ubase + (size_t)(st + 1) * 128;
      xa = *(const float4*)up;
      xb = *(const float4*)(up + 4);
    }

    // ======== phase 2: gates + state update + publish + re-arm LDS ========
    if (tid < 128) {
      const int r = tid >> 4, j16 = tid & 15;
      float m[5], iacc[6];
      #pragma unroll
      for (int g = 0; g < 5; ++g) m[g] = me_s[r * 80 + j16 * 5 + g];
      #pragma unroll
      for (int g = 0; g < 6; ++g) iacc[g] = ie_s[r * 96 + j16 * 6 + g];
      const float hf = hf_own[tid];
      const float hs = hs_own[tid];
      const float a = 1.f + ftanh(iacc[0] + m[0]);
      const float b = 1.5f * (1.f + ftanh(iacc[1] + m[1]));
      const float c = 0.3f + 0.7f * fsig(iacc[2] + m[2]);
      const float d = 0.03f * fsig(iacc[3] + m[3]);
      const float e = 1.f + fsig(iacc[4] + m[4]);
      const float hfn_v = (1.f - c) * hf + c * ftanh(iacc[5] + (a + b * hf * hf - hs) * hf);
      const float eh  = e * hf;
      const float eh2 = eh * eh;
      const float hsn_v = hs * (1.f - d) + d * eh2 * eh2;
      hf_own[tid] = hfn_v;
      hs_own[tid] = hsn_v;
      const unsigned hb = f2bf_bits(hfn_v);
      const unsigned lb = f2bf_bits(hfn_v - bfbits2f(hb));
      const unsigned pk = hb | (lb << 16);
      unsigned* dst = snxt + (size_t)(r0 + r) * 512 + j0 + j16;
      asm volatile("global_store_dword %0, %1, off sc1" :: "v"(dst), "v"(pk) : "memory");
      // re-arm accumulators for step st+1 (exclusive ownership of these elems)
      #pragma unroll
      for (int g = 0; g < 5; ++g) me_s[r * 80 + j16 * 5 + g] = bm_s[j16 * 5 + g];
      #pragma unroll
      for (int g = 0; g < 6; ++g) ie_s[r * 96 + j16 * 6 + g] = bi_s[j16 * 6 + g];
      out[(size_t)(r0 + r) * 524288 + (size_t)st * 512 + j0 + j16] = hfn_v;
      if (st == LSTEP - 1)
        out[(size_t)33554432 + (size_t)(r0 + r) * 512 + j0 + j16] = hfn_v;
    }

    // ======== release: drain state stores, then set our flag ========
    asm volatile("s_waitcnt vmcnt(0)" ::: "memory");
    __syncthreads();   // sync #2 — publishers drained, LDS re-armed
    if (tid == 0) {
      unsigned* fp = myflags + jc;
      const unsigned v = (unsigned)(st + 2);
      asm volatile("global_store_dword %0, %1, off sc1" :: "v"(fp), "v"(v) : "memory");
    }
    if (st + 1 < LSTEP) ie_math(xa, xb);  // adds into ie_s for st+1; poll overlaps
  }
}

extern "C" void kernel_launch(void* const* d_in, const int* in_sizes, int n_in,
                              void* d_out, int out_size, void* d_ws, size_t ws_size,
                              hipStream_t stream) {
  (void)in_sizes; (void)n_in; (void)out_size; (void)ws_size;
  const float* u  = (const float*)d_in[0];
  const float* h0 = (const float*)d_in[1];
  const float* Wi = (const float*)d_in[2];
  const float* bi = (const float*)d_in[3];
  const float* Wm = (const float*)d_in[4];
  const float* bm = (const float*)d_in[5];
  float* out = (float*)d_out;
  unsigned* flags  = (unsigned*)d_ws;                      // [0, 1024)
  unsigned* stateA = (unsigned*)((char*)d_ws + 4096);
  unsigned* stateB = stateA + 32768;
  hipMemsetAsync(d_ws, 0, 4096, stream);
  hipLaunchKernelGGL(fused_scan, dim3(NWG), dim3(NTH), 0, stream,
                     u, h0, Wi, bi, Wm, bm, out, stateA, stateB, flags);
}

// Round 10
// 2961.214 us; speedup vs baseline: 3.9585x; 3.9585x over previous
//
#include <hip/hip_runtime.h>
#include <hip/hip_bf16.h>
#include <cstdint>
#include <cstddef>

#define NWG   256
#define NTH   512
#define LSTEP 1024

typedef __attribute__((ext_vector_type(8))) short short8;
typedef __attribute__((ext_vector_type(4))) float f32x4;
typedef __attribute__((ext_vector_type(4))) unsigned int u32x4;
typedef __attribute__((ext_vector_type(2))) unsigned int u32x2;

__device__ __forceinline__ unsigned f2bf_bits(float x) {
  __hip_bfloat16 h = __float2bfloat16(x);
  return (unsigned)__builtin_bit_cast(unsigned short, h);
}
__device__ __forceinline__ float bfbits2f(unsigned b) {
  return __bfloat162float(__builtin_bit_cast(__hip_bfloat16, (unsigned short)b));
}
__device__ __forceinline__ float ftanh(float x) {
  const float ax = fminf(fabsf(x), 15.f);
  const float e  = __expf(-2.f * ax);
  const float t  = (1.f - e) / (1.f + e);
  return copysignf(t, x);
}
__device__ __forceinline__ float fsig(float x) {
  const float xx = fmaxf(fminf(x, 30.f), -30.f);
  return 1.f / (1.f + __expf(-xx));
}

// ws: stateA u64[64*512] (256KB) | stateB u64[64*512]
// Entry = {lo: pk (bf16 hi|lo), hi: tag}. State(S) tag = S+1, buffer parity S&1.
// Tag stored WITH data by one 8B store => poll==payload, single MALL RT.
// Grid decode: bc = wg & 7 (XCD-local group), jc = wg >> 3.

__global__ void __launch_bounds__(NTH, 2)
fused_scan(const float* __restrict__ u, const float* __restrict__ h0,
           const float* __restrict__ Wi, const float* __restrict__ bi,
           const float* __restrict__ Wm, const float* __restrict__ bm,
           float* __restrict__ out, unsigned long long* __restrict__ stateA,
           unsigned long long* __restrict__ stateB)
{
  __shared__ float part_s[5120];   // [kh8][r8][c80] me MFMA partials
  __shared__ float ie_part[3072];  // [kc4][r8][c96] ie MFMA partials
  __shared__ float hf_own[128];    // [r8][j16]
  __shared__ float hs_own[128];
  __shared__ float bm_s[80];
  __shared__ float bi_s[96];

  const int wg   = blockIdx.x;
  const int bc   = wg & 7;         // batch-group: same-XCD under round-robin
  const int jc   = wg >> 3;        // 32 col-groups
  const int j0   = jc * 16;
  const int r0   = bc * 8;
  const int tid  = threadIdx.x;
  const int w    = tid >> 6;
  const int lane = tid & 63;
  const int colf = lane & 15;
  const int ksub = lane >> 4;
  const int rloc = lane & 7;

  // ---- one-time small LDS ----
  if (tid < 80) bm_s[tid] = bm[(tid % 5) * 512 + j0 + tid / 5];
  if (tid >= 128 && tid < 224) {
    const int c = tid - 128;
    bi_s[c] = bi[(c % 6) * 512 + j0 + c / 6];
  }
  // ---- init own hf/hs, publish State(0) with tag=1 ----
  if (tid < 128) {
    const int r = tid >> 4, j16 = tid & 15;
    const float f = h0[(size_t)(r0 + r) * 512 + j0 + j16];
    const float s = h0[(size_t)32768 + (size_t)(r0 + r) * 512 + j0 + j16];
    hf_own[tid] = f;
    hs_own[tid] = s;
    const unsigned hb = f2bf_bits(f);
    const unsigned lb = f2bf_bits(f - bfbits2f(hb));
    u32x2 pr; pr[0] = hb | (lb << 16); pr[1] = 1u;
    unsigned long long* dst = stateA + (size_t)(r0 + r) * 512 + j0 + j16;
    asm volatile("global_store_dwordx2 %0, %1, off sc1" :: "v"(dst), "v"(pr) : "memory");
  }

  // ---- B-fragment gathers ----
  short8 bh[5][2], bl[5][2];
  #pragma unroll
  for (int nt = 0; nt < 5; ++nt) {
    const int c = nt * 16 + colf;
    const int gcol = (c % 5) * 512 + j0 + c / 5;
    #pragma unroll
    for (int kt = 0; kt < 2; ++kt) {
      #pragma unroll
      for (int j = 0; j < 8; ++j) {
        const int kg = w * 64 + kt * 32 + ksub * 8 + j;
        const float wv = Wm[(size_t)kg * 2560 + gcol];
        const unsigned hb = f2bf_bits(wv);
        bh[nt][kt][j] = (short)hb;
        bl[nt][kt][j] = (short)f2bf_bits(wv - bfbits2f(hb));
      }
    }
  }
  const int iekc = w & 3;
  const int ienh = w >> 2;
  short8 bih[3], bil[3];
  #pragma unroll
  for (int nt = 0; nt < 3; ++nt) {
    const int c = (ienh * 3 + nt) * 16 + colf;
    const int gcol = (c % 6) * 512 + j0 + c / 6;
    #pragma unroll
    for (int j = 0; j < 8; ++j) {
      const int kg = iekc * 32 + ksub * 8 + j;
      const float wv = Wi[(size_t)kg * 3072 + gcol];
      const unsigned hb = f2bf_bits(wv);
      bih[nt][j] = (short)hb;
      bil[nt][j] = (short)f2bf_bits(wv - bfbits2f(hb));
    }
  }

  const float* ubase = u + (size_t)(r0 + rloc) * 131072 + iekc * 32 + ksub * 8;

  // ---- ie math from prefetched registers ----
  auto ie_math = [&](float4 xa, float4 xb) {
    const float xv[8] = {xa.x, xa.y, xa.z, xa.w, xb.x, xb.y, xb.z, xb.w};
    short8 ah, al;
    #pragma unroll
    for (int j = 0; j < 8; ++j) {
      const unsigned hb = f2bf_bits(xv[j]);
      ah[j] = (short)hb;
      al[j] = (short)f2bf_bits(xv[j] - bfbits2f(hb));
    }
    f32x4 acc[3];
    #pragma unroll
    for (int nt = 0; nt < 3; ++nt) { acc[nt][0]=0.f; acc[nt][1]=0.f; acc[nt][2]=0.f; acc[nt][3]=0.f; }
    #pragma unroll
    for (int nt = 0; nt < 3; ++nt) {
      acc[nt] = __builtin_amdgcn_mfma_f32_16x16x32_bf16(ah, bih[nt], acc[nt], 0, 0, 0);
      acc[nt] = __builtin_amdgcn_mfma_f32_16x16x32_bf16(ah, bil[nt], acc[nt], 0, 0, 0);
      acc[nt] = __builtin_amdgcn_mfma_f32_16x16x32_bf16(al, bih[nt], acc[nt], 0, 0, 0);
    }
    if (lane < 32) {
      const int rb = (lane >> 4) * 4;
      #pragma unroll
      for (int nt = 0; nt < 3; ++nt)
        #pragma unroll
        for (int i = 0; i < 4; ++i)
          ie_part[iekc * 768 + (rb + i) * 96 + (ienh * 3 + nt) * 16 + colf] = acc[nt][i];
    }
  };

  // ---- ie(0) ----
  {
    const float4 xa0 = *(const float4*)ubase;
    const float4 xb0 = *(const float4*)(ubase + 4);
    ie_math(xa0, xb0);
  }

  const bool active = (lane & 8) == 0;   // fragment rows 8-15 are padding

  for (int st = 0; st < LSTEP; ++st) {
    const unsigned long long* __restrict__ scur = (st & 1) ? stateB : stateA;
    unsigned long long* __restrict__ snxt       = (st & 1) ? stateA : stateB;

    // ======== phase 1: poll-with-payload, unpack, split-bf16 MFMA ========
    {
      const unsigned tag = (unsigned)(st + 1);
      const unsigned long long* base =
          scur + (size_t)(r0 + rloc) * 512 + w * 64 + ksub * 8;
      u32x4 p0 = {0,0,0,0}, p1 = {0,0,0,0}, p2 = {0,0,0,0}, p3 = {0,0,0,0};
      u32x4 p4 = {0,0,0,0}, p5 = {0,0,0,0}, p6 = {0,0,0,0}, p7 = {0,0,0,0};
      if (active) {
        for (;;) {
          asm volatile("global_load_dwordx4 %0, %1, off sc1"            : "=&v"(p0) : "v"(base) : "memory");
          asm volatile("global_load_dwordx4 %0, %1, off offset:16 sc1"  : "=&v"(p1) : "v"(base) : "memory");
          asm volatile("global_load_dwordx4 %0, %1, off offset:32 sc1"  : "=&v"(p2) : "v"(base) : "memory");
          asm volatile("global_load_dwordx4 %0, %1, off offset:48 sc1"  : "=&v"(p3) : "v"(base) : "memory");
          asm volatile("global_load_dwordx4 %0, %1, off offset:256 sc1" : "=&v"(p4) : "v"(base) : "memory");
          asm volatile("global_load_dwordx4 %0, %1, off offset:272 sc1" : "=&v"(p5) : "v"(base) : "memory");
          asm volatile("global_load_dwordx4 %0, %1, off offset:288 sc1" : "=&v"(p6) : "v"(base) : "memory");
          asm volatile("global_load_dwordx4 %0, %1, off offset:304 sc1" : "=&v"(p7) : "v"(base) : "memory");
          asm volatile("s_waitcnt vmcnt(0)" ::: "memory");
          // rule #18: pin the register-only tag compare AFTER the waitcnt —
          // without this fence hipcc hoists it and stale payload passes.
          __builtin_amdgcn_sched_barrier(0);
          const bool ok = p0[1] >= tag && p0[3] >= tag && p1[1] >= tag && p1[3] >= tag
                       && p2[1] >= tag && p2[3] >= tag && p3[1] >= tag && p3[3] >= tag
                       && p4[1] >= tag && p4[3] >= tag && p5[1] >= tag && p5[3] >= tag
                       && p6[1] >= tag && p6[3] >= tag && p7[1] >= tag && p7[3] >= tag;
          if (__all(ok)) break;
          __builtin_amdgcn_s_sleep(1);
        }
      }
      __builtin_amdgcn_sched_barrier(0);
      short8 ah[2], al[2];
      ah[0][0] = (short)(p0[0] & 0xffffu); al[0][0] = (short)(p0[0] >> 16);
      ah[0][1] = (short)(p0[2] & 0xffffu); al[0][1] = (short)(p0[2] >> 16);
      ah[0][2] = (short)(p1[0] & 0xffffu); al[0][2] = (short)(p1[0] >> 16);
      ah[0][3] = (short)(p1[2] & 0xffffu); al[0][3] = (short)(p1[2] >> 16);
      ah[0][4] = (short)(p2[0] & 0xffffu); al[0][4] = (short)(p2[0] >> 16);
      ah[0][5] = (short)(p2[2] & 0xffffu); al[0][5] = (short)(p2[2] >> 16);
      ah[0][6] = (short)(p3[0] & 0xffffu); al[0][6] = (short)(p3[0] >> 16);
      ah[0][7] = (short)(p3[2] & 0xffffu); al[0][7] = (short)(p3[2] >> 16);
      ah[1][0] = (short)(p4[0] & 0xffffu); al[1][0] = (short)(p4[0] >> 16);
      ah[1][1] = (short)(p4[2] & 0xffffu); al[1][1] = (short)(p4[2] >> 16);
      ah[1][2] = (short)(p5[0] & 0xffffu); al[1][2] = (short)(p5[0] >> 16);
      ah[1][3] = (short)(p5[2] & 0xffffu); al[1][3] = (short)(p5[2] >> 16);
      ah[1][4] = (short)(p6[0] & 0xffffu); al[1][4] = (short)(p6[0] >> 16);
      ah[1][5] = (short)(p6[2] & 0xffffu); al[1][5] = (short)(p6[2] >> 16);
      ah[1][6] = (short)(p7[0] & 0xffffu); al[1][6] = (short)(p7[0] >> 16);
      ah[1][7] = (short)(p7[2] & 0xffffu); al[1][7] = (short)(p7[2] >> 16);
      f32x4 acc[5];
      #pragma unroll
      for (int nt = 0; nt < 5; ++nt) { acc[nt][0]=0.f; acc[nt][1]=0.f; acc[nt][2]=0.f; acc[nt][3]=0.f; }
      #pragma unroll
      for (int nt = 0; nt < 5; ++nt)
        #pragma unroll
        for (int kt = 0; kt < 2; ++kt) {
          acc[nt] = __builtin_amdgcn_mfma_f32_16x16x32_bf16(ah[kt], bh[nt][kt], acc[nt], 0, 0, 0);
          acc[nt] = __builtin_amdgcn_mfma_f32_16x16x32_bf16(ah[kt], bl[nt][kt], acc[nt], 0, 0, 0);
          acc[nt] = __builtin_amdgcn_mfma_f32_16x16x32_bf16(al[kt], bh[nt][kt], acc[nt], 0, 0, 0);
        }
      if (lane < 32) {
        const int rb = (lane >> 4) * 4;
        #pragma unroll
        for (int nt = 0; nt < 5; ++nt)
          #pragma unroll
          for (int i = 0; i < 4; ++i)
            part_s[(w * 8 + rb + i) * 80 + nt * 16 + colf] = acc[nt][i];
      }
    }
    __syncthreads();   // sync #1 — part_s/ie_part complete for step st

    // ---- prefetch u(st+1) (plain loads; compiler manages waitcnt at use) ----
    float4 xa = {0.f, 0.f, 0.f, 0.f}, xb = {0.f, 0.f, 0.f, 0.f};
    if (st + 1 < LSTEP) {
      const float* up = ubase + (size_t)(st + 1) * 128;
      xa = *(const float4*)up;
      xb = *(const float4*)(up + 4);
    }

    // ======== phase 2: fused reduce + gates + tagged publish ========
    if (tid < 128) {
      const int r = tid >> 4, j16 = tid & 15;
      float m[5];
      #pragma unroll
      for (int g = 0; g < 5; ++g) {
        float v = bm_s[j16 * 5 + g];
        #pragma unroll
        for (int kh = 0; kh < 8; ++kh) v += part_s[kh * 640 + r * 80 + j16 * 5 + g];
        m[g] = v;
      }
      float iacc[6];
      #pragma unroll
      for (int g = 0; g < 6; ++g) {
        float v = bi_s[j16 * 6 + g];
        #pragma unroll
        for (int kc = 0; kc < 4; ++kc) v += ie_part[kc * 768 + r * 96 + j16 * 6 + g];
        iacc[g] = v;
      }
      const float hf = hf_own[tid];
      const float hs = hs_own[tid];
      const float a = 1.f + ftanh(iacc[0] + m[0]);
      const float b = 1.5f * (1.f + ftanh(iacc[1] + m[1]));
      const float c = 0.3f + 0.7f * fsig(iacc[2] + m[2]);
      const float d = 0.03f * fsig(iacc[3] + m[3]);
      const float e = 1.f + fsig(iacc[4] + m[4]);
      const float hfn_v = (1.f - c) * hf + c * ftanh(iacc[5] + (a + b * hf * hf - hs) * hf);
      const float eh  = e * hf;
      const float eh2 = eh * eh;
      const float hsn_v = hs * (1.f - d) + d * eh2 * eh2;
      hf_own[tid] = hfn_v;
      hs_own[tid] = hsn_v;
      const unsigned hb = f2bf_bits(hfn_v);
      const unsigned lb = f2bf_bits(hfn_v - bfbits2f(hb));
      u32x2 pr; pr[0] = hb | (lb << 16); pr[1] = (unsigned)(st + 2);
      unsigned long long* dst = snxt + (size_t)(r0 + r) * 512 + j0 + j16;
      asm volatile("global_store_dwordx2 %0, %1, off sc1" :: "v"(dst), "v"(pr) : "memory");
      out[(size_t)(r0 + r) * 524288 + (size_t)st * 512 + j0 + j16] = hfn_v;
      if (st == LSTEP - 1)
        out[(size_t)33554432 + (size_t)(r0 + r) * 512 + j0 + j16] = hfn_v;
    }
    __syncthreads();   // sync #2 — part_s/ie_part free for reuse
    if (st + 1 < LSTEP) ie_math(xa, xb);   // ie_part for st+1
  }
}

extern "C" void kernel_launch(void* const* d_in, const int* in_sizes, int n_in,
                              void* d_out, int out_size, void* d_ws, size_t ws_size,
                              hipStream_t stream) {
  (void)in_sizes; (void)n_in; (void)out_size; (void)ws_size;
  const float* u  = (const float*)d_in[0];
  const float* h0 = (const float*)d_in[1];
  const float* Wi = (const float*)d_in[2];
  const float* bi = (const float*)d_in[3];
  const float* Wm = (const float*)d_in[4];
  const float* bm = (const float*)d_in[5];
  float* out = (float*)d_out;
  unsigned long long* stateA = (unsigned long long*)d_ws;
  unsigned long long* stateB = stateA + 64 * 512;
  hipMemsetAsync(d_ws, 0, 2 * 64 * 512 * 8, stream);  // zero tags both buffers
  hipLaunchKernelGGL(fused_scan, dim3(NWG), dim3(NTH), 0, stream,
                     u, h0, Wi, bi, Wm, bm, out, stateA, stateB);
}